// Round 16
// baseline (338.072 us; speedup 1.0000x reference)
//
#include <hip/hip_runtime.h>

#define B_ 8
#define S_ 1025
#define D_ 768
#define H_ 12
#define KV_ 4
#define HD_ 64
#define NREP 3
#define SCALE_ 0.125f
#define EPS_ 1e-6f
#define SKP 1088   // padded key count (17*64)
#define PST 1096   // bf16 P row stride in LDS ushorts (2192 B)
#define QBLK 16    // q-rows per block
#define NQT 65     // ceil(1025/16)
#define DYNLDS 35072  // 16*PST*2 bytes

typedef __attribute__((ext_vector_type(8))) short bf16x8;
typedef __attribute__((ext_vector_type(4))) float f32x4;

__device__ __forceinline__ unsigned short f2bf(float f) {
  unsigned int u = __builtin_bit_cast(unsigned int, f);
  return (unsigned short)((u + 0x7FFFu + ((u >> 16) & 1u)) >> 16);
}
__device__ __forceinline__ unsigned int pk2(float a, float b) {
  return (unsigned int)f2bf(a) | ((unsigned int)f2bf(b) << 16);
}
__device__ __forceinline__ float bf2f(unsigned short u) {
  return __builtin_bit_cast(float, (unsigned int)u << 16);
}
__device__ __forceinline__ unsigned int cvtpk(float a, float b) {
  unsigned int r;
  asm("v_cvt_pk_bf16_f32 %0, %1, %2" : "=v"(r) : "v"(a), "v"(b));
  return r;
}
// async global->LDS, 16B per lane (wave-uniform LDS base + lane*16; chunk-linear layout).
__device__ __forceinline__ void gload16(const void* g, void* l) {
  __builtin_amdgcn_global_load_lds(
      (const __attribute__((address_space(1))) unsigned int*)g,
      (__attribute__((address_space(3))) unsigned int*)l, 16, 0, 0);
}

__device__ __forceinline__ void barrier_lgkm() {
  __builtin_amdgcn_sched_barrier(0);
  asm volatile("s_waitcnt lgkmcnt(0)" ::: "memory");
  __builtin_amdgcn_s_barrier();
  __builtin_amdgcn_sched_barrier(0);
}

// ---------------- fused casts (one launch) ----------------
#define CX_BLK 6150   // 1,574,400 f32x4 groups / 256
#define CW_BLK 3840   // 983040/256
#define CO_BLK 2304   // 589824/256
__global__ __launch_bounds__(256) void cast_all_kernel(const float* __restrict__ x,
    const float* __restrict__ Wq, const float* __restrict__ Wk, const float* __restrict__ Wv,
    const float* __restrict__ Wo, unsigned short* __restrict__ xb,
    unsigned short* __restrict__ WqkvT, unsigned short* __restrict__ WoT) {
  int bid = blockIdx.x;
  if (bid < CX_BLK) {
    int i = bid * 256 + threadIdx.x;
    if (i < 1574400) {
      f32x4 v = *(const f32x4*)(x + (size_t)i * 4);
      uint2 o;
      o.x = pk2(v[0], v[1]);
      o.y = pk2(v[2], v[3]);
      *(uint2*)(xb + (size_t)i * 4) = o;
    }
  } else if (bid < CX_BLK + CW_BLK) {
    int idx = (bid - CX_BLK) * 256 + threadIdx.x;   // < 983040 = 1280*768
    int n = idx / D_, k = idx % D_;
    float v;
    if (n < 768)       v = Wq[(size_t)k * 768 + n];
    else if (n < 1024) v = Wk[(size_t)k * 256 + (n - 768)];
    else               v = Wv[(size_t)k * 256 + (n - 1024)];
    WqkvT[idx] = f2bf(v);
  } else {
    int idx = (bid - CX_BLK - CW_BLK) * 256 + threadIdx.x;  // < 589824 = 768*768
    int n = idx / D_, k = idx % D_;
    WoT[idx] = f2bf(Wo[(size_t)k * D_ + n]);
  }
}

// ---------------- GEMM: C[M][N] fp32 = A[M][K] bf16 @ BT[N][K] bf16 ----------------
// R16: BM=128, BN=64, BK=64 -> 2x grid (occupancy 2.5->~5 blk/CU), half the barriers
// (12 K-iters for K=768), 24KB LDS, gload16 staging (m97 pattern). 4 waves/block,
// wave w owns rows [w*32, w*32+32) x all 64 cols.
#define BM 128
#define BN 64
#define BK 64
__global__ __launch_bounds__(256) void gemm_bt(const unsigned short* __restrict__ A,
    const unsigned short* __restrict__ BT, float* __restrict__ C, int M, int N, int K) {
  __shared__ unsigned short As[BM * BK];   // 16KB; chunk c: row c>>3, cols (c&7)*8..+8
  __shared__ unsigned short Bs[BN * BK];   // 8KB
  const int nMt = (M + BM - 1) / BM;
  const int tm = blockIdx.x % nMt;
  const int tn = blockIdx.x / nMt;
  const int row0 = tm * BM, col0 = tn * BN;
  const int tid = threadIdx.x;
  const int l = tid & 63, w = tid >> 6;
  const int wr = w * 32;                   // wave's 32 rows
  const int lr = l & 15, lk = (l >> 4) * 8;
  // staging chunks: A = {tid, tid+256, tid+512, tid+768} (1024), B = {tid, tid+256} (512)
  int gar[4], gae[4];
#pragma unroll
  for (int j = 0; j < 4; ++j) {
    int c = tid + j * 256;
    int r = row0 + (c >> 3); if (r >= M) r = M - 1;
    gar[j] = r; gae[j] = (c & 7) * 8;
  }
  const int gb0r = col0 + (tid >> 3),        gb0e = (tid & 7) * 8;
  const int gb1r = col0 + ((tid + 256) >> 3), gb1e = (tid & 7) * 8;  // (tid+256)&7 == tid&7
  f32x4 acc[2][4] = {};
  for (int kt = 0; kt < K; kt += BK) {
    __syncthreads();                               // LDS safe to overwrite
#pragma unroll
    for (int j = 0; j < 4; ++j)
      gload16(A + (size_t)gar[j] * K + kt + gae[j], &As[(tid + j * 256) * 8]);
    gload16(BT + (size_t)gb0r * K + kt + gb0e, &Bs[tid * 8]);
    gload16(BT + (size_t)gb1r * K + kt + gb1e, &Bs[(tid + 256) * 8]);
    __syncthreads();                               // vmcnt(0) drained -> tiles resident
#pragma unroll
    for (int ks = 0; ks < 2; ++ks) {
      bf16x8 af[2], bfr[4];
#pragma unroll
      for (int m = 0; m < 2; ++m)
        af[m] = *(const bf16x8*)&As[(wr + m * 16 + lr) * BK + ks * 32 + lk];
#pragma unroll
      for (int n = 0; n < 4; ++n)
        bfr[n] = *(const bf16x8*)&Bs[(n * 16 + lr) * BK + ks * 32 + lk];
#pragma unroll
      for (int m = 0; m < 2; ++m)
#pragma unroll
        for (int n = 0; n < 4; ++n)
          acc[m][n] = __builtin_amdgcn_mfma_f32_16x16x32_bf16(af[m], bfr[n], acc[m][n], 0, 0, 0);
    }
  }
  const int orow = (l >> 4) * 4;
#pragma unroll
  for (int m = 0; m < 2; ++m)
#pragma unroll
    for (int n = 0; n < 4; ++n)
#pragma unroll
      for (int r = 0; r < 4; ++r) {
        int row = row0 + wr + m * 16 + orow + r;
        int col = col0 + n * 16 + lr;
        if (row < M) C[(size_t)row * N + col] = acc[m][n][r];
      }
}

// ---------------- QKV epilogue: rmsnorm + rope + layouts (+ V pad zeroing) ----------------
__global__ __launch_bounds__(256) void qkv_epilogue(const float* __restrict__ QKV,
    const int* __restrict__ pos_ids, const int* __restrict__ ghp, const int* __restrict__ gwp,
    const float* __restrict__ qw, const float* __restrict__ kw,
    unsigned short* __restrict__ Qb, unsigned short* __restrict__ Kb,
    unsigned short* __restrict__ Vt) {
  if (blockIdx.x < B_ * KV_) {
    unsigned short* vp = Vt + (size_t)blockIdx.x * 64 * SKP;
    for (int idx = threadIdx.x; idx < 64 * 63; idx += 256) {
      int d = idx / 63, s = S_ + idx % 63;
      vp[d * SKP + s] = 0;
    }
  }
  int tok = blockIdx.x * 4 + (threadIdx.x >> 6);
  int l = threadIdx.x & 63;
  if (tok >= B_ * S_) return;
  int b = tok / S_, s = tok % S_;
  const float* rowp = QKV + (size_t)tok * 1280;
  bool rot = (s > 0);
  float cs = 1.f, sn = 0.f;
  if (rot) {
    int gh = ghp[0], gw = gwp[0];
    int pos = pos_ids[tok];
    int hi = (pos / gw) % gh;
    int wi = pos % gw;
    int pi = l >> 1;
    int j = pi < 16 ? pi : pi - 16;
    float invf = exp2f(-(float)j * (13.287712379549449f / 16.f));
    float ang = (pi < 16 ? (float)hi : (float)wi) * invf;
    cs = cosf(ang); sn = sinf(ang);
  }
#pragma unroll
  for (int h = 0; h < H_; ++h) {
    float x = rowp[h * 64 + l];
    float ss = x * x;
    for (int off = 32; off; off >>= 1) ss += __shfl_xor(ss, off);
    float xn = x * rsqrtf(ss * (1.f / 64.f) + EPS_) * qw[l];
    float o = xn;
    if (rot) {
      float p = __shfl_xor(xn, 1);
      o = (l & 1) ? (p * sn + xn * cs) : (xn * cs - p * sn);
    }
    o *= SCALE_;
    Qb[((size_t)(b * H_ + h) * S_ + s) * 64 + l] = f2bf(o);
  }
#pragma unroll
  for (int h = 0; h < KV_; ++h) {
    float x = rowp[768 + h * 64 + l];
    float ss = x * x;
    for (int off = 32; off; off >>= 1) ss += __shfl_xor(ss, off);
    float xn = x * rsqrtf(ss * (1.f / 64.f) + EPS_) * kw[l];
    float o = xn;
    if (rot) {
      float p = __shfl_xor(xn, 1);
      o = (l & 1) ? (p * sn + xn * cs) : (xn * cs - p * sn);
    }
    Kb[((size_t)(b * KV_ + h) * S_ + s) * 64 + l] = f2bf(o);
    float v = rowp[1024 + h * 64 + l];
    Vt[((size_t)(b * KV_ + h) * 64 + l) * SKP + s] = f2bf(v);
  }
}

// ---------------- fused attention (R11/R15 monolith, unchanged) ----------------
__global__ __launch_bounds__(512, 4) void attn_kernel(const unsigned short* __restrict__ Qb,
    const unsigned short* __restrict__ Kb, const unsigned short* __restrict__ Vt,
    unsigned short* __restrict__ ctx, float* __restrict__ attn_out) {
  extern __shared__ unsigned short Psh[];
  __shared__ float partial[4][64][4];
  __shared__ float red[8][16];
  __shared__ unsigned short ctxs[16][64];
  int bid = blockIdx.x;
  int swz = (bid & 7) * 780 + (bid >> 3);
  int qt = swz % NQT;
  int h = (swz / NQT) % H_;
  int b = swz / (NQT * H_);
  int kvh = h / NREP;
  int q0 = qt * QBLK;
  int tid = threadIdx.x;
  int l = tid & 63, w = tid >> 6;
  int lr = l & 15, lk = (l >> 4) * 8;

  const unsigned short* Qbase = Qb + (size_t)(b * H_ + h) * S_ * 64;
  const unsigned short* Kbase = Kb + (size_t)(b * KV_ + kvh) * S_ * 64;
  const unsigned short* Vbase = Vt + (size_t)(b * KV_ + kvh) * 64 * SKP;

  int qrow = q0 + lr; if (qrow >= S_) qrow = S_ - 1;
  bf16x8 qf0 = *(const bf16x8*)(Qbase + (size_t)qrow * 64 + lk);
  bf16x8 qf1 = *(const bf16x8*)(Qbase + (size_t)qrow * 64 + 32 + lk);

  float psum = 0.f;
  {
    const int g4 = (l >> 4) * 4;
    const int kb = (w < 4) ? w * 144 : 576 + (w - 4) * 128;
#pragma unroll
    for (int j = 0; j < 9; ++j) {
      if (w < 4 || j < 8) {
        int kr = kb + j * 16 + lr; if (kr > 1024) kr = 1024;
        const unsigned short* kp = Kbase + (size_t)kr * 64;
        bf16x8 kf0 = *(const bf16x8*)(kp + lk);
        bf16x8 kf1 = *(const bf16x8*)(kp + 32 + lk);
        f32x4 acc = {};
        acc = __builtin_amdgcn_mfma_f32_16x16x32_bf16(kf0, qf0, acc, 0, 0, 0);
        acc = __builtin_amdgcn_mfma_f32_16x16x32_bf16(kf1, qf1, acc, 0, 0, 0);
        int key0 = kb + j * 16 + g4;
        float e0 = (key0     <= 1024) ? __expf(acc[0]) : 0.f;
        float e1 = (key0 + 1 <= 1024) ? __expf(acc[1]) : 0.f;
        float e2 = (key0 + 2 <= 1024) ? __expf(acc[2]) : 0.f;
        float e3 = (key0 + 3 <= 1024) ? __expf(acc[3]) : 0.f;
        psum += (e0 + e1) + (e2 + e3);
        uint2 pw; pw.x = cvtpk(e0, e1); pw.y = cvtpk(e2, e3);
        *(uint2*)&Psh[(size_t)lr * PST + key0] = pw;
      }
    }
  }
  psum += __shfl_xor(psum, 16);
  psum += __shfl_xor(psum, 32);
  if (l < 16) red[w][l] = psum;
  barrier_lgkm();

  float invq;
  {
    float s = 0.f;
#pragma unroll
    for (int j2 = 0; j2 < 8; ++j2) s += red[j2][lr];
    invq = 1.f / s;
  }

  f32x4 accv = {};
  {
    const int d0 = (w & 3) * 16;
    const int kh = (w >> 2) * 544;
    const int prow = lr * PST + kh;
    const unsigned short* vb = Vbase + (size_t)(d0 + lr) * SKP + kh;
#pragma unroll 4
    for (int kc = 0; kc < 17; ++kc) {
      bf16x8 pa = *(const bf16x8*)&Psh[prow + kc * 32 + lk];
      bf16x8 vf = *(const bf16x8*)(vb + kc * 32 + lk);
      accv = __builtin_amdgcn_mfma_f32_16x16x32_bf16(pa, vf, accv, 0, 0, 0);
    }
  }
  if (w >= 4) *(f32x4*)partial[w - 4][l] = accv;
  barrier_lgkm();
  if (w < 4) {
    accv += *(const f32x4*)partial[w][l];
    int rowb = (l >> 4) * 4;
    int d0 = (w & 3) * 16;
#pragma unroll
    for (int r = 0; r < 4; ++r) {
      float iv = __shfl(invq, rowb + r);
      ctxs[rowb + r][d0 + lr] = f2bf(accv[r] * iv);
    }
  }
  barrier_lgkm();
  {
    int t = 2 * w + (l >> 5);
    int q = q0 + t;
    if (q < S_) {
      unsigned int u = *(const unsigned int*)&ctxs[t][2 * (l & 31)];
      *(unsigned int*)(ctx + (size_t)(b * S_ + q) * 768 + h * 64 + 2 * (l & 31)) = u;
    }
  }

#pragma unroll
  for (int rr = 0; rr < 2; ++rr) {
    int rowi = w + rr * 8;
    int q = q0 + rowi;
    if (q < S_) {
      float rinv = __shfl(invq, rowi);
      const unsigned short* Prow = Psh + (size_t)rowi * PST;
      float* gout = attn_out + ((size_t)(b * H_ + h) * S_ + q) * S_;
      int a = (4 - (q & 3)) & 3;
      int nx4 = (1025 - a) >> 2;
      int tl = 1025 - a - 4 * nx4;
      if (l < a) gout[l] = bf2f(Prow[l]) * rinv;
      if (l < tl) { int idx = a + 4 * nx4 + l; gout[idx] = bf2f(Prow[idx]) * rinv; }
      if (a == 0) {
#pragma unroll
        for (int c = 0; c < 4; ++c) {
          int ch = c * 64 + l;
          if (ch < nx4) {
            uint2 u = *(const uint2*)&Prow[4 * ch];
            f32x4 o;
            o[0] = __builtin_bit_cast(float, u.x << 16) * rinv;
            o[1] = __builtin_bit_cast(float, u.x & 0xffff0000u) * rinv;
            o[2] = __builtin_bit_cast(float, u.y << 16) * rinv;
            o[3] = __builtin_bit_cast(float, u.y & 0xffff0000u) * rinv;
            *(f32x4*)(gout + 4 * ch) = o;
          }
        }
      } else if (a == 2) {
#pragma unroll
        for (int c = 0; c < 4; ++c) {
          int ch = c * 64 + l;
          if (ch < nx4) {
            unsigned int u0 = *(const unsigned int*)&Prow[4 * ch + 2];
            unsigned int u1 = *(const unsigned int*)&Prow[4 * ch + 4];
            f32x4 o;
            o[0] = __builtin_bit_cast(float, u0 << 16) * rinv;
            o[1] = __builtin_bit_cast(float, u0 & 0xffff0000u) * rinv;
            o[2] = __builtin_bit_cast(float, u1 << 16) * rinv;
            o[3] = __builtin_bit_cast(float, u1 & 0xffff0000u) * rinv;
            *(f32x4*)(gout + 2 + 4 * ch) = o;
          }
        }
      } else if (a == 1) {
#pragma unroll
        for (int c = 0; c < 4; ++c) {
          int ch = c * 64 + l;
          if (ch < nx4) {
            uint2 d01 = *(const uint2*)&Prow[4 * ch];
            unsigned int d2 = *(const unsigned int*)&Prow[4 * ch + 4];
            unsigned int u0 = __builtin_amdgcn_alignbit(d01.y, d01.x, 16);
            unsigned int u1 = __builtin_amdgcn_alignbit(d2, d01.y, 16);
            f32x4 o;
            o[0] = __builtin_bit_cast(float, u0 << 16) * rinv;
            o[1] = __builtin_bit_cast(float, u0 & 0xffff0000u) * rinv;
            o[2] = __builtin_bit_cast(float, u1 << 16) * rinv;
            o[3] = __builtin_bit_cast(float, u1 & 0xffff0000u) * rinv;
            *(f32x4*)(gout + 1 + 4 * ch) = o;
          }
        }
      } else {
#pragma unroll
        for (int c = 0; c < 4; ++c) {
          int ch = c * 64 + l;
          if (ch < nx4) {
            unsigned int d0 = *(const unsigned int*)&Prow[4 * ch + 2];
            uint2 d12 = *(const uint2*)&Prow[4 * ch + 4];
            unsigned int u0 = __builtin_amdgcn_alignbit(d12.x, d0, 16);
            unsigned int u1 = __builtin_amdgcn_alignbit(d12.y, d12.x, 16);
            f32x4 o;
            o[0] = __builtin_bit_cast(float, u0 << 16) * rinv;
            o[1] = __builtin_bit_cast(float, u0 & 0xffff0000u) * rinv;
            o[2] = __builtin_bit_cast(float, u1 << 16) * rinv;
            o[3] = __builtin_bit_cast(float, u1 & 0xffff0000u) * rinv;
            *(f32x4*)(gout + 3 + 4 * ch) = o;
          }
        }
      }
    }
  }
}

// ---------------- launch ----------------
extern "C" void kernel_launch(void* const* d_in, const int* in_sizes, int n_in,
                              void* d_out, int out_size, void* d_ws, size_t ws_size,
                              hipStream_t stream) {
  const float* hidden = (const float*)d_in[0];
  const int* pos_ids = (const int*)d_in[2];
  const int* ghp = (const int*)d_in[3];
  const int* gwp = (const int*)d_in[4];
  const float* Wq = (const float*)d_in[5];
  const float* Wk = (const float*)d_in[6];
  const float* Wv = (const float*)d_in[7];
  const float* Wo = (const float*)d_in[8];
  const float* qnw = (const float*)d_in[9];
  const float* knw = (const float*)d_in[10];

  char* ws = (char*)d_ws;
  unsigned short* Xb    = (unsigned short*)ws;                   // 12,595,200
  unsigned short* WqkvT = (unsigned short*)(ws + 12595200);      //  1,966,080
  unsigned short* WoT   = (unsigned short*)(ws + 14561280);      //  1,179,648
  float*          QKV   = (float*)(ws + 15740928);               // 41,984,000
  unsigned short* ctx   = (unsigned short*)(ws + 15740928);      // alias (after QKV consumed)
  unsigned short* Qb    = (unsigned short*)(ws + 57724928);      // 12,595,200
  unsigned short* Kb    = (unsigned short*)(ws + 70320128);      //  4,198,400
  unsigned short* Vt    = (unsigned short*)(ws + 74518528);      //  4,456,448

  float* out0 = (float*)d_out;
  float* attn_out = out0 + (size_t)B_ * S_ * D_;

  cast_all_kernel<<<CX_BLK + CW_BLK + CO_BLK, 256, 0, stream>>>(
      hidden, Wq, Wk, Wv, Wo, Xb, WqkvT, WoT);

  gemm_bt<<<65 * 20, 256, 0, stream>>>(Xb, WqkvT, QKV, B_ * S_, 1280, D_);

  qkv_epilogue<<<2050, 256, 0, stream>>>(QKV, pos_ids, ghp, gwp, qnw, knw, Qb, Kb, Vt);

  hipFuncSetAttribute((const void*)attn_kernel,
                      hipFuncAttributeMaxDynamicSharedMemorySize, DYNLDS);
  attn_kernel<<<B_ * H_ * NQT, 512, DYNLDS, stream>>>(Qb, Kb, Vt, ctx, attn_out);

  gemm_bt<<<65 * 12, 256, 0, stream>>>(ctx, WoT, out0, B_ * S_, D_, D_);
}

// Round 17
// 330.149 us; speedup vs baseline: 1.0240x; 1.0240x over previous
//
#include <hip/hip_runtime.h>

#define B_ 8
#define S_ 1025
#define D_ 768
#define H_ 12
#define KV_ 4
#define HD_ 64
#define NREP 3
#define SCALE_ 0.125f
#define EPS_ 1e-6f
#define SKP 1088   // padded key count (17*64)
#define PST 1096   // bf16 P row stride in LDS ushorts (2192 B)
#define QBLK 16    // q-rows per block
#define NQT 65     // ceil(1025/16)
#define DYNLDS 35072  // 16*PST*2 bytes

typedef __attribute__((ext_vector_type(8))) short bf16x8;
typedef __attribute__((ext_vector_type(4))) float f32x4;

__device__ __forceinline__ unsigned short f2bf(float f) {
  unsigned int u = __builtin_bit_cast(unsigned int, f);
  return (unsigned short)((u + 0x7FFFu + ((u >> 16) & 1u)) >> 16);
}
__device__ __forceinline__ unsigned int pk2(float a, float b) {
  return (unsigned int)f2bf(a) | ((unsigned int)f2bf(b) << 16);
}
__device__ __forceinline__ float bf2f(unsigned short u) {
  return __builtin_bit_cast(float, (unsigned int)u << 16);
}
__device__ __forceinline__ unsigned int cvtpk(float a, float b) {
  unsigned int r;
  asm("v_cvt_pk_bf16_f32 %0, %1, %2" : "=v"(r) : "v"(a), "v"(b));
  return r;
}
// async global->LDS, 16B per lane (wave-uniform LDS base + lane*16; chunk-linear layout).
__device__ __forceinline__ void gload16(const void* g, void* l) {
  __builtin_amdgcn_global_load_lds(
      (const __attribute__((address_space(1))) unsigned int*)g,
      (__attribute__((address_space(3))) unsigned int*)l, 16, 0, 0);
}

__device__ __forceinline__ void barrier_lgkm() {
  __builtin_amdgcn_sched_barrier(0);
  asm volatile("s_waitcnt lgkmcnt(0)" ::: "memory");
  __builtin_amdgcn_s_barrier();
  __builtin_amdgcn_sched_barrier(0);
}

// ---------------- fused casts (one launch) ----------------
#define CX_BLK 6150   // 1,574,400 f32x4 groups / 256
#define CW_BLK 3840   // 983040/256
#define CO_BLK 2304   // 589824/256
__global__ __launch_bounds__(256) void cast_all_kernel(const float* __restrict__ x,
    const float* __restrict__ Wq, const float* __restrict__ Wk, const float* __restrict__ Wv,
    const float* __restrict__ Wo, unsigned short* __restrict__ xb,
    unsigned short* __restrict__ WqkvT, unsigned short* __restrict__ WoT) {
  int bid = blockIdx.x;
  if (bid < CX_BLK) {
    int i = bid * 256 + threadIdx.x;
    if (i < 1574400) {
      f32x4 v = *(const f32x4*)(x + (size_t)i * 4);
      uint2 o;
      o.x = pk2(v[0], v[1]);
      o.y = pk2(v[2], v[3]);
      *(uint2*)(xb + (size_t)i * 4) = o;
    }
  } else if (bid < CX_BLK + CW_BLK) {
    int idx = (bid - CX_BLK) * 256 + threadIdx.x;   // < 983040 = 1280*768
    int n = idx / D_, k = idx % D_;
    float v;
    if (n < 768)       v = Wq[(size_t)k * 768 + n];
    else if (n < 1024) v = Wk[(size_t)k * 256 + (n - 768)];
    else               v = Wv[(size_t)k * 256 + (n - 1024)];
    WqkvT[idx] = f2bf(v);
  } else {
    int idx = (bid - CX_BLK - CW_BLK) * 256 + threadIdx.x;  // < 589824 = 768*768
    int n = idx / D_, k = idx % D_;
    WoT[idx] = f2bf(Wo[(size_t)k * D_ + n]);
  }
}

// ---------------- GEMM (R15 config, proven): 128x128, BK=32, gload16 staging ----------
#define BM 128
#define BN 128
#define BK 32
__global__ __launch_bounds__(256) void gemm_bt(const unsigned short* __restrict__ A,
    const unsigned short* __restrict__ BT, float* __restrict__ C, int M, int N, int K) {
  __shared__ unsigned short As[BM * BK];   // 8KB, chunk-linear
  __shared__ unsigned short Bs[BN * BK];
  const int nMt = (M + BM - 1) / BM;
  const int tm = blockIdx.x % nMt;
  const int tn = blockIdx.x / nMt;
  const int row0 = tm * BM, col0 = tn * BN;
  const int tid = threadIdx.x;
  const int l = tid & 63, w = tid >> 6;
  const int wr = (w >> 1) * 64, wc = (w & 1) * 64;
  const int lr = l & 15, lk = (l >> 4) * 8;
  const int c0 = tid, c1 = tid + 256;
  const int r0 = c0 >> 2, e0 = (c0 & 3) * 8;
  const int r1 = c1 >> 2, e1 = (c1 & 3) * 8;
  int ga0 = row0 + r0; if (ga0 >= M) ga0 = M - 1;
  int ga1 = row0 + r1; if (ga1 >= M) ga1 = M - 1;
  const int gb0 = col0 + r0, gb1 = col0 + r1;
  f32x4 acc[4][4] = {};
  for (int kt = 0; kt < K; kt += BK) {
    __syncthreads();
    gload16(A + (size_t)ga0 * K + kt + e0, &As[c0 * 8]);
    gload16(A + (size_t)ga1 * K + kt + e1, &As[c1 * 8]);
    gload16(BT + (size_t)gb0 * K + kt + e0, &Bs[c0 * 8]);
    gload16(BT + (size_t)gb1 * K + kt + e1, &Bs[c1 * 8]);
    __syncthreads();
    bf16x8 af[4], bfr[4];
#pragma unroll
    for (int m = 0; m < 4; ++m)
      af[m] = *(const bf16x8*)&As[(wr + m * 16 + lr) * BK + lk];
#pragma unroll
    for (int n = 0; n < 4; ++n)
      bfr[n] = *(const bf16x8*)&Bs[(wc + n * 16 + lr) * BK + lk];
#pragma unroll
    for (int m = 0; m < 4; ++m)
#pragma unroll
      for (int n = 0; n < 4; ++n)
        acc[m][n] = __builtin_amdgcn_mfma_f32_16x16x32_bf16(af[m], bfr[n], acc[m][n], 0, 0, 0);
  }
  const int orow = (l >> 4) * 4;
#pragma unroll
  for (int m = 0; m < 4; ++m)
#pragma unroll
    for (int n = 0; n < 4; ++n)
#pragma unroll
      for (int r = 0; r < 4; ++r) {
        int row = row0 + wr + m * 16 + orow + r;
        int col = col0 + wc + n * 16 + lr;
        if (row < M) C[(size_t)row * N + col] = acc[m][n][r];
      }
}

// ---------------- QKV epilogue: rmsnorm + rope + layouts (+ V pad zeroing) ----------------
__global__ __launch_bounds__(256) void qkv_epilogue(const float* __restrict__ QKV,
    const int* __restrict__ pos_ids, const int* __restrict__ ghp, const int* __restrict__ gwp,
    const float* __restrict__ qw, const float* __restrict__ kw,
    unsigned short* __restrict__ Qb, unsigned short* __restrict__ Kb,
    unsigned short* __restrict__ Vt) {
  if (blockIdx.x < B_ * KV_) {
    unsigned short* vp = Vt + (size_t)blockIdx.x * 64 * SKP;
    for (int idx = threadIdx.x; idx < 64 * 63; idx += 256) {
      int d = idx / 63, s = S_ + idx % 63;
      vp[d * SKP + s] = 0;
    }
  }
  int tok = blockIdx.x * 4 + (threadIdx.x >> 6);
  int l = threadIdx.x & 63;
  if (tok >= B_ * S_) return;
  int b = tok / S_, s = tok % S_;
  const float* rowp = QKV + (size_t)tok * 1280;
  bool rot = (s > 0);
  float cs = 1.f, sn = 0.f;
  if (rot) {
    int gh = ghp[0], gw = gwp[0];
    int pos = pos_ids[tok];
    int hi = (pos / gw) % gh;
    int wi = pos % gw;
    int pi = l >> 1;
    int j = pi < 16 ? pi : pi - 16;
    float invf = exp2f(-(float)j * (13.287712379549449f / 16.f));
    float ang = (pi < 16 ? (float)hi : (float)wi) * invf;
    cs = cosf(ang); sn = sinf(ang);
  }
#pragma unroll
  for (int h = 0; h < H_; ++h) {
    float x = rowp[h * 64 + l];
    float ss = x * x;
    for (int off = 32; off; off >>= 1) ss += __shfl_xor(ss, off);
    float xn = x * rsqrtf(ss * (1.f / 64.f) + EPS_) * qw[l];
    float o = xn;
    if (rot) {
      float p = __shfl_xor(xn, 1);
      o = (l & 1) ? (p * sn + xn * cs) : (xn * cs - p * sn);
    }
    o *= SCALE_;
    Qb[((size_t)(b * H_ + h) * S_ + s) * 64 + l] = f2bf(o);
  }
#pragma unroll
  for (int h = 0; h < KV_; ++h) {
    float x = rowp[768 + h * 64 + l];
    float ss = x * x;
    for (int off = 32; off; off >>= 1) ss += __shfl_xor(ss, off);
    float xn = x * rsqrtf(ss * (1.f / 64.f) + EPS_) * kw[l];
    float o = xn;
    if (rot) {
      float p = __shfl_xor(xn, 1);
      o = (l & 1) ? (p * sn + xn * cs) : (xn * cs - p * sn);
    }
    Kb[((size_t)(b * KV_ + h) * S_ + s) * 64 + l] = f2bf(o);
    float v = rowp[1024 + h * 64 + l];
    Vt[((size_t)(b * KV_ + h) * 64 + l) * SKP + s] = f2bf(v);
  }
}

// ---------------- fused attention: wave-specialized tail ----------------
// After B1 (P + denominators ready): waves 4-7 stream the 16 attn rows to global
// (4 rows each) WHILE waves 0-3 run PV (each wave one d-block over all 1088 keys).
// No partial combine, 2 barriers total; 37.6KB LDS -> 4 blocks/CU at (512,8).
__global__ __launch_bounds__(512, 8) void attn_kernel(const unsigned short* __restrict__ Qb,
    const unsigned short* __restrict__ Kb, const unsigned short* __restrict__ Vt,
    unsigned short* __restrict__ ctx, float* __restrict__ attn_out) {
  extern __shared__ unsigned short Psh[];   // [16][PST] unnormalized bf16 P
  __shared__ float red[8][16];
  __shared__ unsigned short ctxs[16][64];
  int bid = blockIdx.x;
  int swz = (bid & 7) * 780 + (bid >> 3);
  int qt = swz % NQT;
  int h = (swz / NQT) % H_;
  int b = swz / (NQT * H_);
  int kvh = h / NREP;
  int q0 = qt * QBLK;
  int tid = threadIdx.x;
  int l = tid & 63, w = tid >> 6;
  int lr = l & 15, lk = (l >> 4) * 8;

  const unsigned short* Qbase = Qb + (size_t)(b * H_ + h) * S_ * 64;
  const unsigned short* Kbase = Kb + (size_t)(b * KV_ + kvh) * S_ * 64;
  const unsigned short* Vbase = Vt + (size_t)(b * KV_ + kvh) * 64 * SKP;

  int qrow = q0 + lr; if (qrow >= S_) qrow = S_ - 1;
  bf16x8 qf0 = *(const bf16x8*)(Qbase + (size_t)qrow * 64 + lk);
  bf16x8 qf1 = *(const bf16x8*)(Qbase + (size_t)qrow * 64 + 32 + lk);

  // Phase 1: swapped QK^T -> exp -> bf16 P into LDS (no max pass: |s|<=8 analytically)
  float psum = 0.f;
  {
    const int g4 = (l >> 4) * 4;
    const int kb = (w < 4) ? w * 144 : 576 + (w - 4) * 128;
#pragma unroll
    for (int j = 0; j < 9; ++j) {
      if (w < 4 || j < 8) {
        int kr = kb + j * 16 + lr; if (kr > 1024) kr = 1024;
        const unsigned short* kp = Kbase + (size_t)kr * 64;
        bf16x8 kf0 = *(const bf16x8*)(kp + lk);
        bf16x8 kf1 = *(const bf16x8*)(kp + 32 + lk);
        f32x4 acc = {};
        acc = __builtin_amdgcn_mfma_f32_16x16x32_bf16(kf0, qf0, acc, 0, 0, 0);
        acc = __builtin_amdgcn_mfma_f32_16x16x32_bf16(kf1, qf1, acc, 0, 0, 0);
        int key0 = kb + j * 16 + g4;
        float e0 = (key0     <= 1024) ? __expf(acc[0]) : 0.f;
        float e1 = (key0 + 1 <= 1024) ? __expf(acc[1]) : 0.f;
        float e2 = (key0 + 2 <= 1024) ? __expf(acc[2]) : 0.f;
        float e3 = (key0 + 3 <= 1024) ? __expf(acc[3]) : 0.f;
        psum += (e0 + e1) + (e2 + e3);
        uint2 pw; pw.x = cvtpk(e0, e1); pw.y = cvtpk(e2, e3);
        *(uint2*)&Psh[(size_t)lr * PST + key0] = pw;
      }
    }
  }
  psum += __shfl_xor(psum, 16);
  psum += __shfl_xor(psum, 32);
  if (l < 16) red[w][l] = psum;
  barrier_lgkm();                          // B1: P + red complete

  float invq;                              // lane lr holds inv for row lr
  {
    float s = 0.f;
#pragma unroll
    for (int j2 = 0; j2 < 8; ++j2) s += red[j2][lr];
    invq = 1.f / s;
  }

  if (w < 4) {
    // -------- PV waves: full key range for d-block w*16..+16, 34 kc steps --------
    f32x4 accv = {};
    const int d0 = w * 16;
    const int prow = lr * PST;
    const unsigned short* vb = Vbase + (size_t)(d0 + lr) * SKP;
#pragma unroll 2
    for (int kc = 0; kc < 34; ++kc) {
      bf16x8 pa = *(const bf16x8*)&Psh[prow + kc * 32 + lk];
      bf16x8 vf = *(const bf16x8*)(vb + kc * 32 + lk);
      accv = __builtin_amdgcn_mfma_f32_16x16x32_bf16(pa, vf, accv, 0, 0, 0);
    }
    int rowb = (l >> 4) * 4;
#pragma unroll
    for (int r = 0; r < 4; ++r) {
      float iv = __shfl(invq, rowb + r);   // full wave active
      ctxs[rowb + r][d0 + lr] = f2bf(accv[r] * iv);
    }
  } else {
    // -------- store waves: rows 4*(w-4) .. +3, aligned dwordx4 attn stores --------
#pragma unroll
    for (int rr = 0; rr < 4; ++rr) {
      int rowi = (w - 4) * 4 + rr;
      int q = q0 + rowi;
      if (q < S_) {
        float rinv = __shfl(invq, rowi);   // wave-uniform index, all lanes active
        const unsigned short* Prow = Psh + (size_t)rowi * PST;
        float* gout = attn_out + ((size_t)(b * H_ + h) * S_ + q) * S_;
        int a = (4 - (q & 3)) & 3;
        int nx4 = (1025 - a) >> 2;
        int tl = 1025 - a - 4 * nx4;
        if (l < a) gout[l] = bf2f(Prow[l]) * rinv;
        if (l < tl) { int idx = a + 4 * nx4 + l; gout[idx] = bf2f(Prow[idx]) * rinv; }
        if (a == 0) {
#pragma unroll
          for (int c = 0; c < 4; ++c) {
            int ch = c * 64 + l;
            if (ch < nx4) {
              uint2 u = *(const uint2*)&Prow[4 * ch];
              f32x4 o;
              o[0] = __builtin_bit_cast(float, u.x << 16) * rinv;
              o[1] = __builtin_bit_cast(float, u.x & 0xffff0000u) * rinv;
              o[2] = __builtin_bit_cast(float, u.y << 16) * rinv;
              o[3] = __builtin_bit_cast(float, u.y & 0xffff0000u) * rinv;
              *(f32x4*)(gout + 4 * ch) = o;
            }
          }
        } else if (a == 2) {
#pragma unroll
          for (int c = 0; c < 4; ++c) {
            int ch = c * 64 + l;
            if (ch < nx4) {
              unsigned int u0 = *(const unsigned int*)&Prow[4 * ch + 2];
              unsigned int u1 = *(const unsigned int*)&Prow[4 * ch + 4];
              f32x4 o;
              o[0] = __builtin_bit_cast(float, u0 << 16) * rinv;
              o[1] = __builtin_bit_cast(float, u0 & 0xffff0000u) * rinv;
              o[2] = __builtin_bit_cast(float, u1 << 16) * rinv;
              o[3] = __builtin_bit_cast(float, u1 & 0xffff0000u) * rinv;
              *(f32x4*)(gout + 2 + 4 * ch) = o;
            }
          }
        } else if (a == 1) {
#pragma unroll
          for (int c = 0; c < 4; ++c) {
            int ch = c * 64 + l;
            if (ch < nx4) {
              uint2 d01 = *(const uint2*)&Prow[4 * ch];
              unsigned int d2 = *(const unsigned int*)&Prow[4 * ch + 4];
              unsigned int u0 = __builtin_amdgcn_alignbit(d01.y, d01.x, 16);
              unsigned int u1 = __builtin_amdgcn_alignbit(d2, d01.y, 16);
              f32x4 o;
              o[0] = __builtin_bit_cast(float, u0 << 16) * rinv;
              o[1] = __builtin_bit_cast(float, u0 & 0xffff0000u) * rinv;
              o[2] = __builtin_bit_cast(float, u1 << 16) * rinv;
              o[3] = __builtin_bit_cast(float, u1 & 0xffff0000u) * rinv;
              *(f32x4*)(gout + 1 + 4 * ch) = o;
            }
          }
        } else { // a == 3
#pragma unroll
          for (int c = 0; c < 4; ++c) {
            int ch = c * 64 + l;
            if (ch < nx4) {
              unsigned int d0w = *(const unsigned int*)&Prow[4 * ch + 2];
              uint2 d12 = *(const uint2*)&Prow[4 * ch + 4];
              unsigned int u0 = __builtin_amdgcn_alignbit(d12.x, d0w, 16);
              unsigned int u1 = __builtin_amdgcn_alignbit(d12.y, d12.x, 16);
              f32x4 o;
              o[0] = __builtin_bit_cast(float, u0 << 16) * rinv;
              o[1] = __builtin_bit_cast(float, u0 & 0xffff0000u) * rinv;
              o[2] = __builtin_bit_cast(float, u1 << 16) * rinv;
              o[3] = __builtin_bit_cast(float, u1 & 0xffff0000u) * rinv;
              *(f32x4*)(gout + 3 + 4 * ch) = o;
            }
          }
        }
      }
    }
  }
  barrier_lgkm();                          // B2: ctxs complete (stores still in flight)
  {
    int t = 2 * w + (l >> 5);
    int q = q0 + t;
    if (q < S_) {
      unsigned int u = *(const unsigned int*)&ctxs[t][2 * (l & 31)];
      *(unsigned int*)(ctx + (size_t)(b * S_ + q) * 768 + h * 64 + 2 * (l & 31)) = u;
    }
  }
}

// ---------------- launch ----------------
extern "C" void kernel_launch(void* const* d_in, const int* in_sizes, int n_in,
                              void* d_out, int out_size, void* d_ws, size_t ws_size,
                              hipStream_t stream) {
  const float* hidden = (const float*)d_in[0];
  const int* pos_ids = (const int*)d_in[2];
  const int* ghp = (const int*)d_in[3];
  const int* gwp = (const int*)d_in[4];
  const float* Wq = (const float*)d_in[5];
  const float* Wk = (const float*)d_in[6];
  const float* Wv = (const float*)d_in[7];
  const float* Wo = (const float*)d_in[8];
  const float* qnw = (const float*)d_in[9];
  const float* knw = (const float*)d_in[10];

  char* ws = (char*)d_ws;
  unsigned short* Xb    = (unsigned short*)ws;                   // 12,595,200
  unsigned short* WqkvT = (unsigned short*)(ws + 12595200);      //  1,966,080
  unsigned short* WoT   = (unsigned short*)(ws + 14561280);      //  1,179,648
  float*          QKV   = (float*)(ws + 15740928);               // 41,984,000
  unsigned short* ctx   = (unsigned short*)(ws + 15740928);      // alias (after QKV consumed)
  unsigned short* Qb    = (unsigned short*)(ws + 57724928);      // 12,595,200
  unsigned short* Kb    = (unsigned short*)(ws + 70320128);      //  4,198,400
  unsigned short* Vt    = (unsigned short*)(ws + 74518528);      //  4,456,448

  float* out0 = (float*)d_out;
  float* attn_out = out0 + (size_t)B_ * S_ * D_;

  cast_all_kernel<<<CX_BLK + CW_BLK + CO_BLK, 256, 0, stream>>>(
      hidden, Wq, Wk, Wv, Wo, Xb, WqkvT, WoT);

  gemm_bt<<<65 * 10, 256, 0, stream>>>(Xb, WqkvT, QKV, B_ * S_, 1280, D_);

  qkv_epilogue<<<2050, 256, 0, stream>>>(QKV, pos_ids, ghp, gwp, qnw, knw, Qb, Kb, Vt);

  hipFuncSetAttribute((const void*)attn_kernel,
                      hipFuncAttributeMaxDynamicSharedMemorySize, DYNLDS);
  attn_kernel<<<B_ * H_ * NQT, 512, DYNLDS, stream>>>(Qb, Kb, Vt, ctx, attn_out);

  gemm_bt<<<65 * 6, 256, 0, stream>>>(ctx, WoT, out0, B_ * S_, D_, D_);
}

// Round 19
// 328.376 us; speedup vs baseline: 1.0295x; 1.0054x over previous
//
#include <hip/hip_runtime.h>

#define B_ 8
#define S_ 1025
#define D_ 768
#define H_ 12
#define KV_ 4
#define HD_ 64
#define NREP 3
#define SCALE_ 0.125f
#define EPS_ 1e-6f
#define SKP 1088   // padded key count (17*64)
#define PST 1096   // bf16 P row stride in LDS ushorts (2192 B)
#define QBLK 16    // q-rows per block
#define NQT 65     // ceil(1025/16)
#define DYNLDS 35072  // 16*PST*2 bytes

typedef __attribute__((ext_vector_type(8))) short bf16x8;
typedef __attribute__((ext_vector_type(4))) float f32x4;

__device__ __forceinline__ unsigned short f2bf(float f) {
  unsigned int u = __builtin_bit_cast(unsigned int, f);
  return (unsigned short)((u + 0x7FFFu + ((u >> 16) & 1u)) >> 16);
}
__device__ __forceinline__ unsigned int pk2(float a, float b) {
  return (unsigned int)f2bf(a) | ((unsigned int)f2bf(b) << 16);
}
__device__ __forceinline__ float bf2f(unsigned short u) {
  return __builtin_bit_cast(float, (unsigned int)u << 16);
}
__device__ __forceinline__ unsigned int cvtpk(float a, float b) {
  unsigned int r;
  asm("v_cvt_pk_bf16_f32 %0, %1, %2" : "=v"(r) : "v"(a), "v"(b));
  return r;
}
// async global->LDS, 16B per lane (wave-uniform LDS base + lane*16; chunk-linear layout).
__device__ __forceinline__ void gload16(const void* g, void* l) {
  __builtin_amdgcn_global_load_lds(
      (const __attribute__((address_space(1))) unsigned int*)g,
      (__attribute__((address_space(3))) unsigned int*)l, 16, 0, 0);
}

__device__ __forceinline__ void barrier_lgkm() {
  __builtin_amdgcn_sched_barrier(0);
  asm volatile("s_waitcnt lgkmcnt(0)" ::: "memory");
  __builtin_amdgcn_s_barrier();
  __builtin_amdgcn_sched_barrier(0);
}

// ---------------- fused casts (one launch) ----------------
#define CX_BLK 6150   // 1,574,400 f32x4 groups / 256
#define CW_BLK 3840   // 983040/256
#define CO_BLK 2304   // 589824/256
__global__ __launch_bounds__(256) void cast_all_kernel(const float* __restrict__ x,
    const float* __restrict__ Wq, const float* __restrict__ Wk, const float* __restrict__ Wv,
    const float* __restrict__ Wo, unsigned short* __restrict__ xb,
    unsigned short* __restrict__ WqkvT, unsigned short* __restrict__ WoT) {
  int bid = blockIdx.x;
  if (bid < CX_BLK) {
    int i = bid * 256 + threadIdx.x;
    if (i < 1574400) {
      f32x4 v = *(const f32x4*)(x + (size_t)i * 4);
      uint2 o;
      o.x = pk2(v[0], v[1]);
      o.y = pk2(v[2], v[3]);
      *(uint2*)(xb + (size_t)i * 4) = o;
    }
  } else if (bid < CX_BLK + CW_BLK) {
    int idx = (bid - CX_BLK) * 256 + threadIdx.x;   // < 983040 = 1280*768
    int n = idx / D_, k = idx % D_;
    float v;
    if (n < 768)       v = Wq[(size_t)k * 768 + n];
    else if (n < 1024) v = Wk[(size_t)k * 256 + (n - 768)];
    else               v = Wv[(size_t)k * 256 + (n - 1024)];
    WqkvT[idx] = f2bf(v);
  } else {
    int idx = (bid - CX_BLK - CW_BLK) * 256 + threadIdx.x;  // < 589824 = 768*768
    int n = idx / D_, k = idx % D_;
    WoT[idx] = f2bf(Wo[(size_t)k * D_ + n]);
  }
}

// ---------------- GEMM A (QKV, proven R15): 128x128, BK=32, gload16 staging ----------
#define BM 128
#define BN 128
#define BK 32
__global__ __launch_bounds__(256) void gemm_bt(const unsigned short* __restrict__ A,
    const unsigned short* __restrict__ BT, float* __restrict__ C, int M, int N, int K) {
  __shared__ unsigned short As[BM * BK];
  __shared__ unsigned short Bs[BN * BK];
  const int nMt = (M + BM - 1) / BM;
  const int tm = blockIdx.x % nMt;
  const int tn = blockIdx.x / nMt;
  const int row0 = tm * BM, col0 = tn * BN;
  const int tid = threadIdx.x;
  const int l = tid & 63, w = tid >> 6;
  const int wr = (w >> 1) * 64, wc = (w & 1) * 64;
  const int lr = l & 15, lk = (l >> 4) * 8;
  const int c0 = tid, c1 = tid + 256;
  const int r0 = c0 >> 2, e0 = (c0 & 3) * 8;
  const int r1 = c1 >> 2, e1 = (c1 & 3) * 8;
  int ga0 = row0 + r0; if (ga0 >= M) ga0 = M - 1;
  int ga1 = row0 + r1; if (ga1 >= M) ga1 = M - 1;
  const int gb0 = col0 + r0, gb1 = col0 + r1;
  f32x4 acc[4][4] = {};
  for (int kt = 0; kt < K; kt += BK) {
    __syncthreads();
    gload16(A + (size_t)ga0 * K + kt + e0, &As[c0 * 8]);
    gload16(A + (size_t)ga1 * K + kt + e1, &As[c1 * 8]);
    gload16(BT + (size_t)gb0 * K + kt + e0, &Bs[c0 * 8]);
    gload16(BT + (size_t)gb1 * K + kt + e1, &Bs[c1 * 8]);
    __syncthreads();
    bf16x8 af[4], bfr[4];
#pragma unroll
    for (int m = 0; m < 4; ++m)
      af[m] = *(const bf16x8*)&As[(wr + m * 16 + lr) * BK + lk];
#pragma unroll
    for (int n = 0; n < 4; ++n)
      bfr[n] = *(const bf16x8*)&Bs[(wc + n * 16 + lr) * BK + lk];
#pragma unroll
    for (int m = 0; m < 4; ++m)
#pragma unroll
      for (int n = 0; n < 4; ++n)
        acc[m][n] = __builtin_amdgcn_mfma_f32_16x16x32_bf16(af[m], bfr[n], acc[m][n], 0, 0, 0);
  }
  const int orow = (l >> 4) * 4;
#pragma unroll
  for (int m = 0; m < 4; ++m)
#pragma unroll
    for (int n = 0; n < 4; ++n)
#pragma unroll
      for (int r = 0; r < 4; ++r) {
        int row = row0 + wr + m * 16 + orow + r;
        int col = col0 + wc + n * 16 + lr;
        if (row < M) C[(size_t)row * N + col] = acc[m][n][r];
      }
}

// ---------------- GEMM B (out, proven R16): 128x64, BK=64, gload16 staging ----------
// 2x the blocks of the 128x128 config for the narrow-N output GEMM (N=768 -> 780 blocks).
__global__ __launch_bounds__(256) void gemm_bt64(const unsigned short* __restrict__ A,
    const unsigned short* __restrict__ BT, float* __restrict__ C, int M, int N, int K) {
  __shared__ unsigned short As[128 * 64];   // 16KB; chunk c: row c>>3, cols (c&7)*8..+8
  __shared__ unsigned short Bs[64 * 64];    // 8KB
  const int nMt = (M + 127) / 128;
  const int tm = blockIdx.x % nMt;
  const int tn = blockIdx.x / nMt;
  const int row0 = tm * 128, col0 = tn * 64;
  const int tid = threadIdx.x;
  const int l = tid & 63, w = tid >> 6;
  const int wr = w * 32;                   // wave's 32 rows
  const int lr = l & 15, lk = (l >> 4) * 8;
  int gar[4], gae[4];
#pragma unroll
  for (int j = 0; j < 4; ++j) {
    int c = tid + j * 256;
    int r = row0 + (c >> 3); if (r >= M) r = M - 1;
    gar[j] = r; gae[j] = (c & 7) * 8;
  }
  const int gb0r = col0 + (tid >> 3),         gb0e = (tid & 7) * 8;
  const int gb1r = col0 + ((tid + 256) >> 3), gb1e = (tid & 7) * 8;
  f32x4 acc[2][4] = {};
  for (int kt = 0; kt < K; kt += 64) {
    __syncthreads();
#pragma unroll
    for (int j = 0; j < 4; ++j)
      gload16(A + (size_t)gar[j] * K + kt + gae[j], &As[(tid + j * 256) * 8]);
    gload16(BT + (size_t)gb0r * K + kt + gb0e, &Bs[tid * 8]);
    gload16(BT + (size_t)gb1r * K + kt + gb1e, &Bs[(tid + 256) * 8]);
    __syncthreads();
#pragma unroll
    for (int ks = 0; ks < 2; ++ks) {
      bf16x8 af[2], bfr[4];
#pragma unroll
      for (int m = 0; m < 2; ++m)
        af[m] = *(const bf16x8*)&As[(wr + m * 16 + lr) * 64 + ks * 32 + lk];
#pragma unroll
      for (int n = 0; n < 4; ++n)
        bfr[n] = *(const bf16x8*)&Bs[(n * 16 + lr) * 64 + ks * 32 + lk];
#pragma unroll
      for (int m = 0; m < 2; ++m)
#pragma unroll
        for (int n = 0; n < 4; ++n)
          acc[m][n] = __builtin_amdgcn_mfma_f32_16x16x32_bf16(af[m], bfr[n], acc[m][n], 0, 0, 0);
    }
  }
  const int orow = (l >> 4) * 4;
#pragma unroll
  for (int m = 0; m < 2; ++m)
#pragma unroll
    for (int n = 0; n < 4; ++n)
#pragma unroll
      for (int r = 0; r < 4; ++r) {
        int row = row0 + wr + m * 16 + orow + r;
        int col = col0 + n * 16 + lr;
        if (row < M) C[(size_t)row * N + col] = acc[m][n][r];
      }
}

// ---------------- QKV epilogue: rmsnorm + rope + layouts (+ V pad zeroing) ----------------
__global__ __launch_bounds__(256) void qkv_epilogue(const float* __restrict__ QKV,
    const int* __restrict__ pos_ids, const int* __restrict__ ghp, const int* __restrict__ gwp,
    const float* __restrict__ qw, const float* __restrict__ kw,
    unsigned short* __restrict__ Qb, unsigned short* __restrict__ Kb,
    unsigned short* __restrict__ Vt) {
  if (blockIdx.x < B_ * KV_) {
    unsigned short* vp = Vt + (size_t)blockIdx.x * 64 * SKP;
    for (int idx = threadIdx.x; idx < 64 * 63; idx += 256) {
      int d = idx / 63, s = S_ + idx % 63;
      vp[d * SKP + s] = 0;
    }
  }
  int tok = blockIdx.x * 4 + (threadIdx.x >> 6);
  int l = threadIdx.x & 63;
  if (tok >= B_ * S_) return;
  int b = tok / S_, s = tok % S_;
  const float* rowp = QKV + (size_t)tok * 1280;
  bool rot = (s > 0);
  float cs = 1.f, sn = 0.f;
  if (rot) {
    int gh = ghp[0], gw = gwp[0];
    int pos = pos_ids[tok];
    int hi = (pos / gw) % gh;
    int wi = pos % gw;
    int pi = l >> 1;
    int j = pi < 16 ? pi : pi - 16;
    float invf = exp2f(-(float)j * (13.287712379549449f / 16.f));
    float ang = (pi < 16 ? (float)hi : (float)wi) * invf;
    cs = cosf(ang); sn = sinf(ang);
  }
#pragma unroll
  for (int h = 0; h < H_; ++h) {
    float x = rowp[h * 64 + l];
    float ss = x * x;
    for (int off = 32; off; off >>= 1) ss += __shfl_xor(ss, off);
    float xn = x * rsqrtf(ss * (1.f / 64.f) + EPS_) * qw[l];
    float o = xn;
    if (rot) {
      float p = __shfl_xor(xn, 1);
      o = (l & 1) ? (p * sn + xn * cs) : (xn * cs - p * sn);
    }
    o *= SCALE_;
    Qb[((size_t)(b * H_ + h) * S_ + s) * 64 + l] = f2bf(o);
  }
#pragma unroll
  for (int h = 0; h < KV_; ++h) {
    float x = rowp[768 + h * 64 + l];
    float ss = x * x;
    for (int off = 32; off; off >>= 1) ss += __shfl_xor(ss, off);
    float xn = x * rsqrtf(ss * (1.f / 64.f) + EPS_) * kw[l];
    float o = xn;
    if (rot) {
      float p = __shfl_xor(xn, 1);
      o = (l & 1) ? (p * sn + xn * cs) : (xn * cs - p * sn);
    }
    Kb[((size_t)(b * KV_ + h) * S_ + s) * 64 + l] = f2bf(o);
    float v = rowp[1024 + h * 64 + l];
    Vt[((size_t)(b * KV_ + h) * 64 + l) * SKP + s] = f2bf(v);
  }
}

// ---------------- fused attention (R17, proven @330us): wave-specialized tail --------
__global__ __launch_bounds__(512, 8) void attn_kernel(const unsigned short* __restrict__ Qb,
    const unsigned short* __restrict__ Kb, const unsigned short* __restrict__ Vt,
    unsigned short* __restrict__ ctx, float* __restrict__ attn_out) {
  extern __shared__ unsigned short Psh[];   // [16][PST] unnormalized bf16 P
  __shared__ float red[8][16];
  __shared__ unsigned short ctxs[16][64];
  int bid = blockIdx.x;
  int swz = (bid & 7) * 780 + (bid >> 3);
  int qt = swz % NQT;
  int h = (swz / NQT) % H_;
  int b = swz / (NQT * H_);
  int kvh = h / NREP;
  int q0 = qt * QBLK;
  int tid = threadIdx.x;
  int l = tid & 63, w = tid >> 6;
  int lr = l & 15, lk = (l >> 4) * 8;

  const unsigned short* Qbase = Qb + (size_t)(b * H_ + h) * S_ * 64;
  const unsigned short* Kbase = Kb + (size_t)(b * KV_ + kvh) * S_ * 64;
  const unsigned short* Vbase = Vt + (size_t)(b * KV_ + kvh) * 64 * SKP;

  int qrow = q0 + lr; if (qrow >= S_) qrow = S_ - 1;
  bf16x8 qf0 = *(const bf16x8*)(Qbase + (size_t)qrow * 64 + lk);
  bf16x8 qf1 = *(const bf16x8*)(Qbase + (size_t)qrow * 64 + 32 + lk);

  float psum = 0.f;
  {
    const int g4 = (l >> 4) * 4;
    const int kb = (w < 4) ? w * 144 : 576 + (w - 4) * 128;
#pragma unroll
    for (int j = 0; j < 9; ++j) {
      if (w < 4 || j < 8) {
        int kr = kb + j * 16 + lr; if (kr > 1024) kr = 1024;
        const unsigned short* kp = Kbase + (size_t)kr * 64;
        bf16x8 kf0 = *(const bf16x8*)(kp + lk);
        bf16x8 kf1 = *(const bf16x8*)(kp + 32 + lk);
        f32x4 acc = {};
        acc = __builtin_amdgcn_mfma_f32_16x16x32_bf16(kf0, qf0, acc, 0, 0, 0);
        acc = __builtin_amdgcn_mfma_f32_16x16x32_bf16(kf1, qf1, acc, 0, 0, 0);
        int key0 = kb + j * 16 + g4;
        float e0 = (key0     <= 1024) ? __expf(acc[0]) : 0.f;
        float e1 = (key0 + 1 <= 1024) ? __expf(acc[1]) : 0.f;
        float e2 = (key0 + 2 <= 1024) ? __expf(acc[2]) : 0.f;
        float e3 = (key0 + 3 <= 1024) ? __expf(acc[3]) : 0.f;
        psum += (e0 + e1) + (e2 + e3);
        uint2 pw; pw.x = cvtpk(e0, e1); pw.y = cvtpk(e2, e3);
        *(uint2*)&Psh[(size_t)lr * PST + key0] = pw;
      }
    }
  }
  psum += __shfl_xor(psum, 16);
  psum += __shfl_xor(psum, 32);
  if (l < 16) red[w][l] = psum;
  barrier_lgkm();                          // B1: P + red complete

  float invq;                              // lane lr holds inv for row lr
  {
    float s = 0.f;
#pragma unroll
    for (int j2 = 0; j2 < 8; ++j2) s += red[j2][lr];
    invq = 1.f / s;
  }

  if (w < 4) {
    // -------- PV waves: full key range for d-block w*16..+16, 34 kc steps --------
    f32x4 accv = {};
    const int d0 = w * 16;
    const int prow = lr * PST;
    const unsigned short* vb = Vbase + (size_t)(d0 + lr) * SKP;
#pragma unroll 2
    for (int kc = 0; kc < 34; ++kc) {
      bf16x8 pa = *(const bf16x8*)&Psh[prow + kc * 32 + lk];
      bf16x8 vf = *(const bf16x8*)(vb + kc * 32 + lk);
      accv = __builtin_amdgcn_mfma_f32_16x16x32_bf16(pa, vf, accv, 0, 0, 0);
    }
    int rowb = (l >> 4) * 4;
#pragma unroll
    for (int r = 0; r < 4; ++r) {
      float iv = __shfl(invq, rowb + r);   // full wave active
      ctxs[rowb + r][d0 + lr] = f2bf(accv[r] * iv);
    }
  } else {
    // -------- store waves: rows 4*(w-4) .. +3, aligned dwordx4 attn stores --------
#pragma unroll
    for (int rr = 0; rr < 4; ++rr) {
      int rowi = (w - 4) * 4 + rr;
      int q = q0 + rowi;
      if (q < S_) {
        float rinv = __shfl(invq, rowi);   // wave-uniform index, all lanes active
        const unsigned short* Prow = Psh + (size_t)rowi * PST;
        float* gout = attn_out + ((size_t)(b * H_ + h) * S_ + q) * S_;
        int a = (4 - (q & 3)) & 3;
        int nx4 = (1025 - a) >> 2;
        int tl = 1025 - a - 4 * nx4;
        if (l < a) gout[l] = bf2f(Prow[l]) * rinv;
        if (l < tl) { int idx = a + 4 * nx4 + l; gout[idx] = bf2f(Prow[idx]) * rinv; }
        if (a == 0) {
#pragma unroll
          for (int c = 0; c < 4; ++c) {
            int ch = c * 64 + l;
            if (ch < nx4) {
              uint2 u = *(const uint2*)&Prow[4 * ch];
              f32x4 o;
              o[0] = __builtin_bit_cast(float, u.x << 16) * rinv;
              o[1] = __builtin_bit_cast(float, u.x & 0xffff0000u) * rinv;
              o[2] = __builtin_bit_cast(float, u.y << 16) * rinv;
              o[3] = __builtin_bit_cast(float, u.y & 0xffff0000u) * rinv;
              *(f32x4*)(gout + 4 * ch) = o;
            }
          }
        } else if (a == 2) {
#pragma unroll
          for (int c = 0; c < 4; ++c) {
            int ch = c * 64 + l;
            if (ch < nx4) {
              unsigned int u0 = *(const unsigned int*)&Prow[4 * ch + 2];
              unsigned int u1 = *(const unsigned int*)&Prow[4 * ch + 4];
              f32x4 o;
              o[0] = __builtin_bit_cast(float, u0 << 16) * rinv;
              o[1] = __builtin_bit_cast(float, u0 & 0xffff0000u) * rinv;
              o[2] = __builtin_bit_cast(float, u1 << 16) * rinv;
              o[3] = __builtin_bit_cast(float, u1 & 0xffff0000u) * rinv;
              *(f32x4*)(gout + 2 + 4 * ch) = o;
            }
          }
        } else if (a == 1) {
#pragma unroll
          for (int c = 0; c < 4; ++c) {
            int ch = c * 64 + l;
            if (ch < nx4) {
              uint2 d01 = *(const uint2*)&Prow[4 * ch];
              unsigned int d2 = *(const unsigned int*)&Prow[4 * ch + 4];
              unsigned int u0 = __builtin_amdgcn_alignbit(d01.y, d01.x, 16);
              unsigned int u1 = __builtin_amdgcn_alignbit(d2, d01.y, 16);
              f32x4 o;
              o[0] = __builtin_bit_cast(float, u0 << 16) * rinv;
              o[1] = __builtin_bit_cast(float, u0 & 0xffff0000u) * rinv;
              o[2] = __builtin_bit_cast(float, u1 << 16) * rinv;
              o[3] = __builtin_bit_cast(float, u1 & 0xffff0000u) * rinv;
              *(f32x4*)(gout + 1 + 4 * ch) = o;
            }
          }
        } else { // a == 3
#pragma unroll
          for (int c = 0; c < 4; ++c) {
            int ch = c * 64 + l;
            if (ch < nx4) {
              unsigned int d0w = *(const unsigned int*)&Prow[4 * ch + 2];
              uint2 d12 = *(const uint2*)&Prow[4 * ch + 4];
              unsigned int u0 = __builtin_amdgcn_alignbit(d12.x, d0w, 16);
              unsigned int u1 = __builtin_amdgcn_alignbit(d12.y, d12.x, 16);
              f32x4 o;
              o[0] = __builtin_bit_cast(float, u0 << 16) * rinv;
              o[1] = __builtin_bit_cast(float, u0 & 0xffff0000u) * rinv;
              o[2] = __builtin_bit_cast(float, u1 << 16) * rinv;
              o[3] = __builtin_bit_cast(float, u1 & 0xffff0000u) * rinv;
              *(f32x4*)(gout + 3 + 4 * ch) = o;
            }
          }
        }
      }
    }
  }
  barrier_lgkm();                          // B2: ctxs complete (stores still in flight)
  {
    int t = 2 * w + (l >> 5);
    int q = q0 + t;
    if (q < S_) {
      unsigned int u = *(const unsigned int*)&ctxs[t][2 * (l & 31)];
      *(unsigned int*)(ctx + (size_t)(b * S_ + q) * 768 + h * 64 + 2 * (l & 31)) = u;
    }
  }
}

// ---------------- launch ----------------
extern "C" void kernel_launch(void* const* d_in, const int* in_sizes, int n_in,
                              void* d_out, int out_size, void* d_ws, size_t ws_size,
                              hipStream_t stream) {
  const float* hidden = (const float*)d_in[0];
  const int* pos_ids = (const int*)d_in[2];
  const int* ghp = (const int*)d_in[3];
  const int* gwp = (const int*)d_in[4];
  const float* Wq = (const float*)d_in[5];
  const float* Wk = (const float*)d_in[6];
  const float* Wv = (const float*)d_in[7];
  const float* Wo = (const float*)d_in[8];
  const float* qnw = (const float*)d_in[9];
  const float* knw = (const float*)d_in[10];

  char* ws = (char*)d_ws;
  unsigned short* Xb    = (unsigned short*)ws;                   // 12,595,200
  unsigned short* WqkvT = (unsigned short*)(ws + 12595200);      //  1,966,080
  unsigned short* WoT   = (unsigned short*)(ws + 14561280);      //  1,179,648
  float*          QKV   = (float*)(ws + 15740928);               // 41,984,000
  unsigned short* ctx   = (unsigned short*)(ws + 15740928);      // alias (after QKV consumed)
  unsigned short* Qb    = (unsigned short*)(ws + 57724928);      // 12,595,200
  unsigned short* Kb    = (unsigned short*)(ws + 70320128);      //  4,198,400
  unsigned short* Vt    = (unsigned short*)(ws + 74518528);      //  4,456,448

  float* out0 = (float*)d_out;
  float* attn_out = out0 + (size_t)B_ * S_ * D_;

  cast_all_kernel<<<CX_BLK + CW_BLK + CO_BLK, 256, 0, stream>>>(
      hidden, Wq, Wk, Wv, Wo, Xb, WqkvT, WoT);

  gemm_bt<<<65 * 10, 256, 0, stream>>>(Xb, WqkvT, QKV, B_ * S_, 1280, D_);

  qkv_epilogue<<<2050, 256, 0, stream>>>(QKV, pos_ids, ghp, gwp, qnw, knw, Qb, Kb, Vt);

  hipFuncSetAttribute((const void*)attn_kernel,
                      hipFuncAttributeMaxDynamicSharedMemorySize, DYNLDS);
  attn_kernel<<<B_ * H_ * NQT, 512, DYNLDS, stream>>>(Qb, Kb, Vt, ctx, attn_out);

  gemm_bt64<<<65 * 12, 256, 0, stream>>>(ctx, WoT, out0, B_ * S_, D_, D_);
}